// Round 3
// baseline (5975.019 us; speedup 1.0000x reference)
//
#include <hip/hip_runtime.h>
#include <hip/hip_bf16.h>
#include <cstdint>

#define NN 50000
#define NE 800000

typedef _Float16 f16;
typedef f16 f16x8 __attribute__((ext_vector_type(8)));
typedef f16 f16x4 __attribute__((ext_vector_type(4)));
typedef float f32x4 __attribute__((ext_vector_type(4)));

// ============================================================================
// Weight pre-pack (f16 MFMA fragment layout; A/B frag layouts are symmetric).
// unit = kc*8 + ct ; element [lane][i] = W[kc*32 + (lane>>4)*8 + i][ct*16 + (lane&15)]
// Edge pack per layer: et_w1 72 units | et_w2 32 | msg_w1 32 | msg_w2 32 = 168
// ============================================================================
__global__ void pack_w_kernel(const float* __restrict__ et_w1,
                              const float* __restrict__ et_w2,
                              const float* __restrict__ msg_w1,
                              const float* __restrict__ msg_w2,
                              f16* __restrict__ wpack) {
  int idx = blockIdx.x * 256 + threadIdx.x;
  if (idx >= 4 * 86016) return;
  int l = idx / 86016;
  int rem = idx - l * 86016;
  int unit = rem >> 9;
  int e = rem & 511;
  int ln = e >> 3, i = e & 7;
  const float* src;
  int ul;
  if (unit < 72)       { src = et_w1  + (size_t)l * 288 * 128; ul = unit; }
  else if (unit < 104) { src = et_w2  + (size_t)l * 128 * 128; ul = unit - 72; }
  else if (unit < 136) { src = msg_w1 + (size_t)l * 128 * 128; ul = unit - 104; }
  else                 { src = msg_w2 + (size_t)l * 128 * 128; ul = unit - 136; }
  int kc = ul >> 3, ct = ul & 7;
  int k = kc * 32 + (ln >> 4) * 8 + i;
  int col = ct * 16 + (ln & 15);
  wpack[idx] = (f16)src[k * 128 + col];
}

// Update pack per layer: upd_w1 (K=256) 64 units | upd_w2 32 units = 96
__global__ void pack_upd_kernel(const float* __restrict__ upd_w1,
                                const float* __restrict__ upd_w2,
                                f16* __restrict__ wpu) {
  int idx = blockIdx.x * 256 + threadIdx.x;
  if (idx >= 4 * 96 * 512) return;
  int l = idx / (96 * 512);
  int rem = idx - l * (96 * 512);
  int unit = rem >> 9, e = rem & 511, ln = e >> 3, i = e & 7;
  const float* src;
  int ul;
  if (unit < 64) { src = upd_w1 + (size_t)l * 256 * 128; ul = unit; }
  else           { src = upd_w2 + (size_t)l * 128 * 128; ul = unit - 64; }
  int kc = ul >> 3, ct = ul & 7;
  int k = kc * 32 + (ln >> 4) * 8 + i;
  int col = ct * 16 + (ln & 15);
  wpu[idx] = (f16)src[k * 128 + col];
}

// ============================================================================
// Transposed-D MFMA GEMM: D = W_frag x edge_frag  ->  D[n][m]
// lane holds: m (row of data) = cl per 16-tile, n = kh*4 + reg (4 consecutive!)
// Wave wv owns output features [wv*32, wv*32+32) for ALL 64 rows.
// acc[nt][et]: nt = feature 16-tile (2), et = data-row 16-tile (4).
// A-source read: row r, k-slice kc*32+kh*8; XOR-swizzle when ASWZ (stride 128).
// ============================================================================
#define MFMA_T(APTR, ASTR, ASWZ, NKC, UNIT0, BIAS)                             \
  {                                                                            \
    _Pragma("unroll") for (int nt = 0; nt < 2; ++nt) {                         \
      f32x4 bv_ = *(const f32x4*)((BIAS) + wv * 32 + nt * 16 + kh * 4);        \
      _Pragma("unroll") for (int et = 0; et < 4; ++et) acc[nt][et] = bv_;      \
    }                                                                          \
    _Pragma("unroll 2") for (int kc = 0; kc < (NKC); ++kc) {                   \
      f16x8 wfr_[2];                                                           \
      _Pragma("unroll") for (int nt = 0; nt < 2; ++nt)                         \
        wfr_[nt] = *(const f16x8*)&wp[(size_t)(((UNIT0) + kc * 8 + wv * 2 + nt) * 64 + lane) * 8]; \
      _Pragma("unroll") for (int et = 0; et < 4; ++et) {                       \
        int r_ = et * 16 + cl;                                                 \
        int idx_ = r_ * (ASTR) + kc * 32 + kh * 8;                             \
        if (ASWZ) idx_ ^= ((r_ & 7) << 3);                                     \
        f16x8 efr_ = *(const f16x8*)&(APTR)[idx_];                             \
        _Pragma("unroll") for (int nt = 0; nt < 2; ++nt)                       \
          acc[nt][et] = __builtin_amdgcn_mfma_f32_16x16x32_f16(wfr_[nt], efr_, acc[nt][et], 0, 0, 0); \
      }                                                                        \
    }                                                                          \
  }

// Store D^T tile to [64][128] f16 LDS (XOR swizzled): one 8B write per tile.
#define STORE_T(DPTR, RELU)                                                    \
  _Pragma("unroll") for (int nt = 0; nt < 2; ++nt)                             \
    _Pragma("unroll") for (int et = 0; et < 4; ++et) {                         \
      float v0_ = acc[nt][et][0], v1_ = acc[nt][et][1],                        \
            v2_ = acc[nt][et][2], v3_ = acc[nt][et][3];                        \
      if (RELU) { v0_ = fmaxf(v0_, 0.f); v1_ = fmaxf(v1_, 0.f);                \
                  v2_ = fmaxf(v2_, 0.f); v3_ = fmaxf(v3_, 0.f); }              \
      int r_ = et * 16 + cl;                                                   \
      int idx_ = (r_ * 128 + wv * 32 + nt * 16 + kh * 4) ^ ((r_ & 7) << 3);    \
      *(f16x4*)&(DPTR)[idx_] = (f16x4){(f16)v0_, (f16)v1_, (f16)v2_, (f16)v3_};\
    }

// ============================================================================
// Fused edge pipeline: 64 edges/block, 4 waves, f16 MFMA, 3 blocks/CU.
// ============================================================================
__global__ __launch_bounds__(256, 3)
void edge_mfma_kernel(const f16* __restrict__ h16, const float* __restrict__ ea,
                      const int* __restrict__ esrc, const int* __restrict__ edst,
                      const f16* __restrict__ wp,
                      const float* __restrict__ b1, const float* __restrict__ b2,
                      const float* __restrict__ b3, const float* __restrict__ b4,
                      float* __restrict__ aggr) {
  __shared__ f16 ein[64 * 288];   // e_in [64][288]; reused as e_emb [64][128] swz
  __shared__ f16 tb[64 * 128];    // XOR-swizzled intermediate
  __shared__ int eidx[128];       // [0:64) dst, [64:128) src
  const int tid = threadIdx.x;
  const int lane = tid & 63;
  const int wv = tid >> 6;
  const int cl = lane & 15;
  const int kh = lane >> 4;
  const int e0 = blockIdx.x * 64;
  if (tid < 64) eidx[tid] = edst[e0 + tid];
  else if (tid < 128) eidx[tid] = esrc[e0 + tid - 64];
  __syncthreads();
  // stage e_in = [h16[dst] | h16[src] | cvt(ea)] : [64 rows][36 x 8-f16 chunks]
#pragma unroll
  for (int it = 0; it < 9; ++it) {
    int f = tid + it * 256;
    int row = f / 36, c8 = f - row * 36;
    f16x8 v;
    if (c8 < 16) {
      v = *(const f16x8*)(h16 + (size_t)eidx[row] * 128 + c8 * 8);
    } else if (c8 < 32) {
      v = *(const f16x8*)(h16 + (size_t)eidx[64 + row] * 128 + (c8 - 16) * 8);
    } else {
      const float* sp = ea + (size_t)(e0 + row) * 32 + (c8 - 32) * 8;
      float4 u0 = *(const float4*)sp, u1 = *(const float4*)(sp + 4);
      v = (f16x8){(f16)u0.x, (f16)u0.y, (f16)u0.z, (f16)u0.w,
                  (f16)u1.x, (f16)u1.y, (f16)u1.z, (f16)u1.w};
    }
    *(f16x8*)&ein[row * 288 + c8 * 8] = v;
  }
  __syncthreads();
  f32x4 acc[2][4];
  MFMA_T(ein, 288, 0, 9, 0, b1);            // et hidden, K=288
  STORE_T(tb, 1);
  __syncthreads();
  MFMA_T(tb, 128, 1, 4, 72, b2);            // e_emb, K=128
  STORE_T(ein, 0);                          // e_emb into ein region (swz 128)
  __syncthreads();
  MFMA_T(ein, 128, 1, 4, 104, b3);          // msg hidden, K=128
  STORE_T(tb, 1);
  __syncthreads();
  MFMA_T(tb, 128, 1, 4, 136, b4);           // msg, K=128
  // atomic scatter: lane holds 4 consecutive features of edge row et*16+cl
#pragma unroll
  for (int nt = 0; nt < 2; ++nt) {
#pragma unroll
    for (int et = 0; et < 4; ++et) {
      int m = et * 16 + cl;
      float* ap = aggr + (size_t)eidx[m] * 128 + wv * 32 + nt * 16 + kh * 4;
#pragma unroll
      for (int i = 0; i < 4; ++i) unsafeAtomicAdd(ap + i, acc[nt][et][i]);
    }
  }
}

// ============================================================================
// update: h' = LN(h + MLP2([h|aggr]))  -- f16 MFMA, writes h16 only
// ============================================================================
__global__ __launch_bounds__(256, 2)
void update_mfma_kernel(const f16* __restrict__ h16, const float* __restrict__ aggr,
                        const f16* __restrict__ wp,
                        const float* __restrict__ b1, const float* __restrict__ b2,
                        const float* __restrict__ lng, const float* __restrict__ lnb,
                        f16* __restrict__ h16out) {
  __shared__ f16 ua[64 * 264];    // [64][256] input (stride 264, bank-balanced)
  __shared__ f16 tb[64 * 128];    // swz
  __shared__ f16 emb[64 * 128];   // swz, MLP output
  const int tid = threadIdx.x;
  const int lane = tid & 63;
  const int wv = tid >> 6;
  const int cl = lane & 15;
  const int kh = lane >> 4;
  const int r0 = blockIdx.x * 64;
  // stage [h16 | cvt(aggr)] : [64][32 chunks]
#pragma unroll
  for (int it = 0; it < 8; ++it) {
    int f = tid + it * 256;
    int row = f >> 5, c8 = f & 31;
    int grow = r0 + row;
    f16x8 v = {};
    if (grow < NN) {
      if (c8 < 16) {
        v = *(const f16x8*)(h16 + (size_t)grow * 128 + c8 * 8);
      } else {
        const float* sp = aggr + (size_t)grow * 128 + (c8 - 16) * 8;
        float4 u0 = *(const float4*)sp, u1 = *(const float4*)(sp + 4);
        v = (f16x8){(f16)u0.x, (f16)u0.y, (f16)u0.z, (f16)u0.w,
                    (f16)u1.x, (f16)u1.y, (f16)u1.z, (f16)u1.w};
      }
    }
    *(f16x8*)&ua[row * 264 + c8 * 8] = v;
  }
  __syncthreads();
  f32x4 acc[2][4];
  MFMA_T(ua, 264, 0, 8, 0, b1);             // upd hidden, K=256
  STORE_T(tb, 1);
  __syncthreads();
  MFMA_T(tb, 128, 1, 4, 64, b2);            // h_new, K=128
  STORE_T(emb, 0);
  __syncthreads();
  // LN epilogue: thread -> (row = tid>>2, quarter q = tid&3 -> 32 cols)
  {
    const int row = tid >> 2, q = tid & 3;
    const int grow = r0 + row;
    float y[32];
    float s = 0.f, ss = 0.f;
#pragma unroll
    for (int j = 0; j < 4; ++j) {
      int col = q * 32 + j * 8;
      int ei = (row * 128 + col) ^ ((row & 7) << 3);
      f16x8 ev = *(const f16x8*)&emb[ei];
      f16x8 rv = *(const f16x8*)&ua[row * 264 + col];   // residual = f16(h)
#pragma unroll
      for (int e = 0; e < 8; ++e) {
        float t = (float)ev[e] + (float)rv[e];
        y[j * 8 + e] = t; s += t; ss += t * t;
      }
    }
    s += __shfl_xor(s, 1);  s += __shfl_xor(s, 2);
    ss += __shfl_xor(ss, 1); ss += __shfl_xor(ss, 2);
    float mean = s * (1.f / 128.f);
    float var = ss * (1.f / 128.f) - mean * mean;
    float rstd = rsqrtf(var + 1e-5f);
    if (grow < NN) {
#pragma unroll
      for (int j = 0; j < 4; ++j) {
        int col = q * 32 + j * 8;
        const float4 g0 = *(const float4*)(lng + col), g1 = *(const float4*)(lng + col + 4);
        const float4 q0 = *(const float4*)(lnb + col), q1 = *(const float4*)(lnb + col + 4);
        float gv[8] = {g0.x, g0.y, g0.z, g0.w, g1.x, g1.y, g1.z, g1.w};
        float bv[8] = {q0.x, q0.y, q0.z, q0.w, q1.x, q1.y, q1.z, q1.w};
        f16x8 o;
#pragma unroll
        for (int e = 0; e < 8; ++e)
          o[e] = (f16)((y[j * 8 + e] - mean) * rstd * gv[e] + bv[e]);
        *(f16x8*)(h16out + (size_t)grow * 128 + col) = o;
      }
    }
  }
}

// ============================================================================
// fp32 register-tiled machinery (encoder only)
// ============================================================================
#define ACC_INIT(BPTR)                                                        \
  {                                                                           \
    const float4 bA_ = *(const float4*)((BPTR) + cg * 8);                     \
    const float4 bB_ = *(const float4*)((BPTR) + cg * 8 + 4);                 \
    _Pragma("unroll") for (int i_ = 0; i_ < 4; ++i_) {                        \
      acc[i_][0] = bA_.x; acc[i_][1] = bA_.y; acc[i_][2] = bA_.z;             \
      acc[i_][3] = bA_.w; acc[i_][4] = bB_.x; acc[i_][5] = bB_.y;             \
      acc[i_][6] = bB_.z; acc[i_][7] = bB_.w;                                 \
    }                                                                         \
  }

#define GEMM_STEP(ABUF, ASTR, WPTR)                                           \
  {                                                                           \
    const float4 w0_ = *(const float4*)((WPTR) + (size_t)k * 128 + cg * 8);   \
    const float4 w1_ = *(const float4*)((WPTR) + (size_t)k * 128 + cg * 8 + 4);\
    float wv_[8] = {w0_.x, w0_.y, w0_.z, w0_.w, w1_.x, w1_.y, w1_.z, w1_.w};  \
    float av_[4];                                                             \
    _Pragma("unroll") for (int i_ = 0; i_ < 4; ++i_)                          \
        av_[i_] = (ABUF)[(rg * 4 + i_) * (ASTR) + k];                         \
    _Pragma("unroll") for (int i_ = 0; i_ < 4; ++i_)                          \
      _Pragma("unroll") for (int j_ = 0; j_ < 8; ++j_)                        \
          acc[i_][j_] = fmaf(av_[i_], wv_[j_], acc[i_][j_]);                  \
  }

#define STORE_LDS_RELU(TBUF, TSTR)                                            \
  _Pragma("unroll") for (int i_ = 0; i_ < 4; ++i_) {                          \
    *(float4*)&(TBUF)[(rg * 4 + i_) * (TSTR) + cg * 8] =                      \
        make_float4(fmaxf(acc[i_][0], 0.f), fmaxf(acc[i_][1], 0.f),           \
                    fmaxf(acc[i_][2], 0.f), fmaxf(acc[i_][3], 0.f));          \
    *(float4*)&(TBUF)[(rg * 4 + i_) * (TSTR) + cg * 8 + 4] =                  \
        make_float4(fmaxf(acc[i_][4], 0.f), fmaxf(acc[i_][5], 0.f),           \
                    fmaxf(acc[i_][6], 0.f), fmaxf(acc[i_][7], 0.f));          \
  }

__global__ void gru_transpose_kernel(const float* __restrict__ wih,
                                     const float* __restrict__ whh,
                                     float* __restrict__ wihT,
                                     float* __restrict__ whhT) {
  int idx = blockIdx.x * 256 + threadIdx.x;
  if (idx < 128 * 384) {
    int k = idx / 384;
    int j = idx - k * 384;
    wihT[idx] = wih[j * 128 + k];
    whhT[idx] = whh[j * 128 + k];
  }
}

// encoder: h16 = f16(relu(x@W1+b1)@W2+b2)
__global__ __launch_bounds__(256, 2)
void encoder_kernel(const float* __restrict__ x,
                    const float* __restrict__ w1, const float* __restrict__ b1,
                    const float* __restrict__ w2, const float* __restrict__ b2,
                    f16* __restrict__ h16out) {
  __shared__ float xa[64 * 132];
  __shared__ float tb[64 * 132];
  const int tid = threadIdx.x;
  const int cg = tid & 15, rg = tid >> 4;
  const int r0 = blockIdx.x * 64;
#pragma unroll
  for (int it = 0; it < 8; ++it) {
    int f = tid + it * 256;
    int row = f >> 5, c4 = f & 31;
    float4 v = make_float4(0.f, 0.f, 0.f, 0.f);
    int grow = r0 + row;
    if (grow < NN) v = *(const float4*)(x + (size_t)grow * 128 + c4 * 4);
    *(float4*)&xa[row * 132 + c4 * 4] = v;
  }
  __syncthreads();
  float acc[4][8];
  ACC_INIT(b1);
#pragma unroll 2
  for (int k = 0; k < 128; ++k) GEMM_STEP(xa, 132, w1);
  STORE_LDS_RELU(tb, 132);
  __syncthreads();
  ACC_INIT(b2);
#pragma unroll 2
  for (int k = 0; k < 128; ++k) GEMM_STEP(tb, 132, w2);
#pragma unroll
  for (int i = 0; i < 4; ++i) {
    int grow = r0 + rg * 4 + i;
    if (grow < NN) {
      f16x8 o = {(f16)acc[i][0], (f16)acc[i][1], (f16)acc[i][2], (f16)acc[i][3],
                 (f16)acc[i][4], (f16)acc[i][5], (f16)acc[i][6], (f16)acc[i][7]};
      *(f16x8*)(h16out + (size_t)grow * 128 + cg * 8) = o;
    }
  }
}

// GRU cell (torch semantics); h input is f16, h_prev f32
__global__ __launch_bounds__(256, 4)
void gru_kernel(const f16* __restrict__ h16, const float* __restrict__ hprev,
                const float* __restrict__ wihT, const float* __restrict__ whhT,
                const float* __restrict__ bih, const float* __restrict__ bhh,
                float* __restrict__ out) {
  __shared__ float ha[32 * 132];
  __shared__ float hp[32 * 132];
  const int tid = threadIdx.x, cg = tid & 15, rg = tid >> 4;
  const int r0 = blockIdx.x * 32;
#pragma unroll
  for (int it = 0; it < 2; ++it) {
    int f = tid + it * 256;          // [32][16] f16x8 chunks
    int row = f >> 4, c8 = f & 15;
    int grow = r0 + row;
    f16x8 v = {};
    if (grow < NN) v = *(const f16x8*)(h16 + (size_t)grow * 128 + c8 * 8);
    float* dp = &ha[row * 132 + c8 * 8];
    *(float4*)dp = make_float4((float)v[0], (float)v[1], (float)v[2], (float)v[3]);
    *(float4*)(dp + 4) = make_float4((float)v[4], (float)v[5], (float)v[6], (float)v[7]);
  }
#pragma unroll
  for (int it = 0; it < 4; ++it) {
    int f = tid + it * 256;
    int row = f >> 5, c4 = f & 31;
    int grow = r0 + row;
    float4 vp = make_float4(0.f, 0.f, 0.f, 0.f);
    if (grow < NN) vp = *(const float4*)(hprev + (size_t)grow * 128 + c4 * 4);
    *(float4*)&hp[row * 132 + c4 * 4] = vp;
  }
  __syncthreads();
  float rgate[2][8], zgate[2][8];
#pragma unroll
  for (int c = 0; c < 2; ++c) {
    float acc[2][8];
#pragma unroll
    for (int j = 0; j < 8; ++j) {
      float bsum = bih[c * 128 + cg * 8 + j] + bhh[c * 128 + cg * 8 + j];
      acc[0][j] = bsum; acc[1][j] = bsum;
    }
    for (int k = 0; k < 128; ++k) {
      const float* wi = wihT + (size_t)k * 384 + c * 128 + cg * 8;
      const float* wh = whhT + (size_t)k * 384 + c * 128 + cg * 8;
      const float4 wi0 = *(const float4*)wi, wi1 = *(const float4*)(wi + 4);
      const float4 wh0 = *(const float4*)wh, wh1 = *(const float4*)(wh + 4);
      float wiv[8] = {wi0.x, wi0.y, wi0.z, wi0.w, wi1.x, wi1.y, wi1.z, wi1.w};
      float whv[8] = {wh0.x, wh0.y, wh0.z, wh0.w, wh1.x, wh1.y, wh1.z, wh1.w};
      float a0 = ha[(rg * 2 + 0) * 132 + k], a1 = ha[(rg * 2 + 1) * 132 + k];
      float p0 = hp[(rg * 2 + 0) * 132 + k], p1 = hp[(rg * 2 + 1) * 132 + k];
#pragma unroll
      for (int j = 0; j < 8; ++j) {
        acc[0][j] = fmaf(a0, wiv[j], acc[0][j]);
        acc[1][j] = fmaf(a1, wiv[j], acc[1][j]);
        acc[0][j] = fmaf(p0, whv[j], acc[0][j]);
        acc[1][j] = fmaf(p1, whv[j], acc[1][j]);
      }
    }
#pragma unroll
    for (int i = 0; i < 2; ++i)
#pragma unroll
      for (int j = 0; j < 8; ++j) {
        float sg = 1.f / (1.f + __expf(-acc[i][j]));
        if (c == 0) rgate[i][j] = sg; else zgate[i][j] = sg;
      }
  }
  float ai[2][8], ah[2][8];
#pragma unroll
  for (int j = 0; j < 8; ++j) {
    float bi = bih[256 + cg * 8 + j], bh = bhh[256 + cg * 8 + j];
    ai[0][j] = bi; ai[1][j] = bi;
    ah[0][j] = bh; ah[1][j] = bh;
  }
  for (int k = 0; k < 128; ++k) {
    const float* wi = wihT + (size_t)k * 384 + 256 + cg * 8;
    const float* wh = whhT + (size_t)k * 384 + 256 + cg * 8;
    const float4 wi0 = *(const float4*)wi, wi1 = *(const float4*)(wi + 4);
    const float4 wh0 = *(const float4*)wh, wh1 = *(const float4*)(wh + 4);
    float wiv[8] = {wi0.x, wi0.y, wi0.z, wi0.w, wi1.x, wi1.y, wi1.z, wi1.w};
    float whv[8] = {wh0.x, wh0.y, wh0.z, wh0.w, wh1.x, wh1.y, wh1.z, wh1.w};
    float a0 = ha[(rg * 2 + 0) * 132 + k], a1 = ha[(rg * 2 + 1) * 132 + k];
    float p0 = hp[(rg * 2 + 0) * 132 + k], p1 = hp[(rg * 2 + 1) * 132 + k];
#pragma unroll
    for (int j = 0; j < 8; ++j) {
      ai[0][j] = fmaf(a0, wiv[j], ai[0][j]);
      ai[1][j] = fmaf(a1, wiv[j], ai[1][j]);
      ah[0][j] = fmaf(p0, whv[j], ah[0][j]);
      ah[1][j] = fmaf(p1, whv[j], ah[1][j]);
    }
  }
#pragma unroll
  for (int i = 0; i < 2; ++i) {
    int grow = r0 + rg * 2 + i;
    if (grow >= NN) continue;
    float o[8];
#pragma unroll
    for (int j = 0; j < 8; ++j) {
      float nn_ = tanhf(fmaf(rgate[i][j], ah[i][j], ai[i][j]));
      float hpv = hp[(rg * 2 + i) * 132 + cg * 8 + j];
      o[j] = (1.f - zgate[i][j]) * nn_ + zgate[i][j] * hpv;
    }
    *(float4*)(out + (size_t)grow * 128 + cg * 8) = make_float4(o[0], o[1], o[2], o[3]);
    *(float4*)(out + (size_t)grow * 128 + cg * 8 + 4) = make_float4(o[4], o[5], o[6], o[7]);
  }
}

// ---------------- launch ----------------
extern "C" void kernel_launch(void* const* d_in, const int* in_sizes, int n_in,
                              void* d_out, int out_size, void* d_ws, size_t ws_size,
                              hipStream_t stream) {
  (void)in_sizes; (void)n_in; (void)out_size; (void)ws_size;
  const float* x         = (const float*)d_in[0];
  const float* edge_attr = (const float*)d_in[1];
  const float* h_prev    = (const float*)d_in[2];
  const float* enc_w1    = (const float*)d_in[3];
  const float* enc_b1    = (const float*)d_in[4];
  const float* enc_w2    = (const float*)d_in[5];
  const float* enc_b2    = (const float*)d_in[6];
  const float* et_w1     = (const float*)d_in[7];
  const float* et_b1     = (const float*)d_in[8];
  const float* et_w2     = (const float*)d_in[9];
  const float* et_b2     = (const float*)d_in[10];
  const float* msg_w1    = (const float*)d_in[11];
  const float* msg_b1    = (const float*)d_in[12];
  const float* msg_w2    = (const float*)d_in[13];
  const float* msg_b2    = (const float*)d_in[14];
  const float* upd_w1    = (const float*)d_in[15];
  const float* upd_b1    = (const float*)d_in[16];
  const float* upd_w2    = (const float*)d_in[17];
  const float* upd_b2    = (const float*)d_in[18];
  const float* ln_g      = (const float*)d_in[19];
  const float* ln_b      = (const float*)d_in[20];
  const float* gru_wih   = (const float*)d_in[21];
  const float* gru_whh   = (const float*)d_in[22];
  const float* gru_bih   = (const float*)d_in[23];
  const float* gru_bhh   = (const float*)d_in[24];
  const int* edge_index  = (const int*)d_in[25];
  const int* esrc = edge_index;        // edge_index[0]
  const int* edst = edge_index + NE;   // edge_index[1]

  float* ws   = (float*)d_ws;
  float* aggr = ws;                                  // N*128 f32
  float* wihT = ws + (size_t)NN * 128;               // 128*384
  float* whhT = wihT + 128 * 384;                    // 128*384
  f16*   h16a = (f16*)(whhT + 128 * 384);            // N*128 f16
  f16*   h16b = h16a + (size_t)NN * 128;             // N*128 f16
  f16*   wpe  = h16b + (size_t)NN * 128;             // 4*168*512 f16
  f16*   wpu  = wpe + 4 * 86016;                     // 4*96*512 f16

  gru_transpose_kernel<<<192, 256, 0, stream>>>(gru_wih, gru_whh, wihT, whhT);
  pack_w_kernel<<<(4 * 86016 + 255) / 256, 256, 0, stream>>>(et_w1, et_w2, msg_w1, msg_w2, wpe);
  pack_upd_kernel<<<(4 * 96 * 512 + 255) / 256, 256, 0, stream>>>(upd_w1, upd_w2, wpu);
  encoder_kernel<<<(NN + 63) / 64, 256, 0, stream>>>(x, enc_w1, enc_b1, enc_w2, enc_b2, h16a);

  f16* hc = h16a;
  f16* hn = h16b;
  for (int l = 0; l < 4; ++l) {
    hipMemsetAsync(aggr, 0, (size_t)NN * 128 * sizeof(float), stream);
    edge_mfma_kernel<<<NE / 64, 256, 0, stream>>>(
        hc, edge_attr, esrc, edst,
        wpe + (size_t)l * 86016,
        et_b1 + l * 128, et_b2 + l * 128,
        msg_b1 + l * 128, msg_b2 + l * 128,
        aggr);
    update_mfma_kernel<<<(NN + 63) / 64, 256, 0, stream>>>(
        hc, aggr,
        wpu + (size_t)l * 96 * 512,
        upd_b1 + l * 128, upd_b2 + l * 128,
        ln_g, ln_b, hn);
    f16* t = hc; hc = hn; hn = t;
  }
  // after 4 swaps: hc == h16a
  gru_kernel<<<(NN + 31) / 32, 256, 0, stream>>>(hc, h_prev, wihT, whhT,
                                                 gru_bih, gru_bhh, (float*)d_out);
}

// Round 4
// 2050.500 us; speedup vs baseline: 2.9139x; 2.9139x over previous
//
#include <hip/hip_runtime.h>
#include <hip/hip_bf16.h>
#include <cstdint>

#define NN 50000
#define NE 800000

typedef _Float16 f16;
typedef f16 f16x8 __attribute__((ext_vector_type(8)));
typedef f16 f16x4 __attribute__((ext_vector_type(4)));
typedef float f32x4 __attribute__((ext_vector_type(4)));

#define TB_STR 136   // f16 stride for [64][128] intermediates (272B, R2-measured OK)

// ============================================================================
// Weight pre-pack (f16 MFMA fragment layout; A/B frag layouts symmetric).
// unit = kc*8 + ct ; element [lane][i] = W[kc*32 + (lane>>4)*8 + i][ct*16 + (lane&15)]
// Edge pack per layer: et_w1 72 units | et_w2 32 | msg_w1 32 | msg_w2 32 = 168
// ============================================================================
__global__ void pack_w_kernel(const float* __restrict__ et_w1,
                              const float* __restrict__ et_w2,
                              const float* __restrict__ msg_w1,
                              const float* __restrict__ msg_w2,
                              f16* __restrict__ wpack) {
  int idx = blockIdx.x * 256 + threadIdx.x;
  if (idx >= 4 * 86016) return;
  int l = idx / 86016;
  int rem = idx - l * 86016;
  int unit = rem >> 9;
  int e = rem & 511;
  int ln = e >> 3, i = e & 7;
  const float* src;
  int ul;
  if (unit < 72)       { src = et_w1  + (size_t)l * 288 * 128; ul = unit; }
  else if (unit < 104) { src = et_w2  + (size_t)l * 128 * 128; ul = unit - 72; }
  else if (unit < 136) { src = msg_w1 + (size_t)l * 128 * 128; ul = unit - 104; }
  else                 { src = msg_w2 + (size_t)l * 128 * 128; ul = unit - 136; }
  int kc = ul >> 3, ct = ul & 7;
  int k = kc * 32 + (ln >> 4) * 8 + i;
  int col = ct * 16 + (ln & 15);
  wpack[idx] = (f16)src[k * 128 + col];
}

// Update pack per layer: upd_w1 (K=256) 64 units | upd_w2 32 units = 96
__global__ void pack_upd_kernel(const float* __restrict__ upd_w1,
                                const float* __restrict__ upd_w2,
                                f16* __restrict__ wpu) {
  int idx = blockIdx.x * 256 + threadIdx.x;
  if (idx >= 4 * 96 * 512) return;
  int l = idx / (96 * 512);
  int rem = idx - l * (96 * 512);
  int unit = rem >> 9, e = rem & 511, ln = e >> 3, i = e & 7;
  const float* src;
  int ul;
  if (unit < 64) { src = upd_w1 + (size_t)l * 256 * 128; ul = unit; }
  else           { src = upd_w2 + (size_t)l * 128 * 128; ul = unit - 64; }
  int kc = ul >> 3, ct = ul & 7;
  int k = kc * 32 + (ln >> 4) * 8 + i;
  int col = ct * 16 + (ln & 15);
  wpu[idx] = (f16)src[k * 128 + col];
}

// ============================================================================
// Edge kernel: R2 orientation (D-normal). Wave (wr,wc): rows wr*32..+32,
// cols wc*64..+64. acc[rt][ct], rt=row 16-tile, ct=col 16-tile.
// A-frag: lane(cl,kh) -> row ..+cl, k=kc*32+kh*8..+8.
// C/D: lane holds col=ct*16+cl, rows rt*16+kh*4+{0..3}  (m89-verified).
// ============================================================================
#define EDGE_ACC_INIT(BIAS)                                                    \
  _Pragma("unroll") for (int ct = 0; ct < 4; ++ct) {                           \
    float bv_ = (BIAS)[wc * 64 + ct * 16 + cl];                                \
    acc[0][ct] = (f32x4){bv_, bv_, bv_, bv_};                                  \
    acc[1][ct] = acc[0][ct];                                                   \
  }

#define EDGE_MFMA_KC(A0, A1, UNIT)                                             \
  _Pragma("unroll") for (int ct = 0; ct < 4; ++ct) {                           \
    f16x8 b_ = *(const f16x8*)&wp[(size_t)(((UNIT) + wc * 4 + ct) * 64 + lane) * 8]; \
    acc[0][ct] = __builtin_amdgcn_mfma_f32_16x16x32_f16(A0, b_, acc[0][ct], 0, 0, 0); \
    acc[1][ct] = __builtin_amdgcn_mfma_f32_16x16x32_f16(A1, b_, acc[1][ct], 0, 0, 0); \
  }

// GEMM with A from LDS (stride TB_STR), K=128
#define EDGE_GEMM_LDS(APTR, UNIT0, BIAS)                                       \
  {                                                                            \
    EDGE_ACC_INIT(BIAS);                                                       \
    _Pragma("unroll") for (int kc = 0; kc < 4; ++kc) {                         \
      f16x8 a0_ = *(const f16x8*)&(APTR)[(wr * 32 + cl) * TB_STR + kc * 32 + kh * 8]; \
      f16x8 a1_ = *(const f16x8*)&(APTR)[(wr * 32 + 16 + cl) * TB_STR + kc * 32 + kh * 8]; \
      EDGE_MFMA_KC(a0_, a1_, (UNIT0) + kc * 8);                                \
    }                                                                          \
  }

// scalar f16 C-store to LDS (R2-measured acceptable)
#define EDGE_STORE(DST, RELU)                                                  \
  _Pragma("unroll") for (int rt = 0; rt < 2; ++rt)                             \
    _Pragma("unroll") for (int ct = 0; ct < 4; ++ct)                           \
      _Pragma("unroll") for (int i = 0; i < 4; ++i) {                          \
        float v_ = acc[rt][ct][i];                                             \
        if (RELU) v_ = fmaxf(v_, 0.f);                                         \
        (DST)[(wr * 32 + rt * 16 + kh * 4 + i) * TB_STR + wc * 64 + ct * 16 + cl] = (f16)v_; \
      }

__global__ __launch_bounds__(256, 4)
void edge_mfma_kernel(const f16* __restrict__ h16, const float* __restrict__ ea,
                      const int* __restrict__ esrc, const int* __restrict__ edst,
                      const f16* __restrict__ wp,
                      const float* __restrict__ b1, const float* __restrict__ b2,
                      const float* __restrict__ b3, const float* __restrict__ b4,
                      float* __restrict__ aggr) {
  __shared__ f16 tb[64 * TB_STR];
  __shared__ f16 emb[64 * TB_STR];
  __shared__ int eidx[128];       // [0:64) dst, [64:128) src
  const int tid = threadIdx.x;
  const int lane = tid & 63;
  const int wv = tid >> 6;
  const int wr = wv >> 1, wc = wv & 1;
  const int cl = lane & 15;
  const int kh = lane >> 4;
  const int e0 = blockIdx.x * 64;
  if (tid < 64) eidx[tid] = edst[e0 + tid];
  else if (tid < 128) eidx[tid] = esrc[e0 + tid - 64];
  __syncthreads();

  const int r0 = wr * 32 + cl, r1 = r0 + 16;
  const f16* pd0 = h16 + (size_t)eidx[r0] * 128 + kh * 8;       // x_i = h[dst]
  const f16* pd1 = h16 + (size_t)eidx[r1] * 128 + kh * 8;
  const f16* ps0 = h16 + (size_t)eidx[64 + r0] * 128 + kh * 8;  // x_j = h[src]
  const f16* ps1 = h16 + (size_t)eidx[64 + r1] * 128 + kh * 8;

  f32x4 acc[2][4];
  // ---- GEMM1: et hidden, K=288, A direct from global (no LDS staging) ----
  EDGE_ACC_INIT(b1);
#pragma unroll
  for (int kc = 0; kc < 4; ++kc) {                  // k in [0,128): h[dst]
    f16x8 a0_ = *(const f16x8*)(pd0 + kc * 32);
    f16x8 a1_ = *(const f16x8*)(pd1 + kc * 32);
    EDGE_MFMA_KC(a0_, a1_, kc * 8);
  }
#pragma unroll
  for (int kc = 4; kc < 8; ++kc) {                  // k in [128,256): h[src]
    f16x8 a0_ = *(const f16x8*)(ps0 + (kc - 4) * 32);
    f16x8 a1_ = *(const f16x8*)(ps1 + (kc - 4) * 32);
    EDGE_MFMA_KC(a0_, a1_, kc * 8);
  }
  {                                                  // k in [256,288): edge_attr
    const float* q0 = ea + (size_t)(e0 + r0) * 32 + kh * 8;
    const float* q1 = ea + (size_t)(e0 + r1) * 32 + kh * 8;
    float4 u00 = *(const float4*)q0, u01 = *(const float4*)(q0 + 4);
    float4 u10 = *(const float4*)q1, u11 = *(const float4*)(q1 + 4);
    f16x8 a0_ = {(f16)u00.x, (f16)u00.y, (f16)u00.z, (f16)u00.w,
                 (f16)u01.x, (f16)u01.y, (f16)u01.z, (f16)u01.w};
    f16x8 a1_ = {(f16)u10.x, (f16)u10.y, (f16)u10.z, (f16)u10.w,
                 (f16)u11.x, (f16)u11.y, (f16)u11.z, (f16)u11.w};
    EDGE_MFMA_KC(a0_, a1_, 64);
  }
  EDGE_STORE(tb, 1);
  __syncthreads();
  // ---- GEMM2: e_emb, K=128 ----
  EDGE_GEMM_LDS(tb, 72, b2);
  EDGE_STORE(emb, 0);
  __syncthreads();
  // ---- GEMM3: msg hidden, K=128 ----
  EDGE_GEMM_LDS(emb, 104, b3);
  EDGE_STORE(tb, 1);
  __syncthreads();
  // ---- GEMM4: msg, K=128 -> atomic scatter (R2 pattern: contiguous runs) ----
  EDGE_GEMM_LDS(tb, 136, b4);
#pragma unroll
  for (int rt = 0; rt < 2; ++rt) {
#pragma unroll
    for (int i = 0; i < 4; ++i) {
      int row = wr * 32 + rt * 16 + kh * 4 + i;
      float* ap = aggr + (size_t)eidx[row] * 128 + wc * 64 + cl;
#pragma unroll
      for (int ct = 0; ct < 4; ++ct)
        unsafeAtomicAdd(ap + ct * 16, acc[rt][ct][i]);
    }
  }
}

// ============================================================================
// Transposed-D MFMA machinery (update kernel only; no atomics there)
// ============================================================================
#define MFMA_T(APTR, ASTR, ASWZ, NKC, UNIT0, BIAS)                             \
  {                                                                            \
    _Pragma("unroll") for (int nt = 0; nt < 2; ++nt) {                         \
      f32x4 bv_ = *(const f32x4*)((BIAS) + wv * 32 + nt * 16 + kh * 4);        \
      _Pragma("unroll") for (int et = 0; et < 4; ++et) acc[nt][et] = bv_;      \
    }                                                                          \
    _Pragma("unroll 2") for (int kc = 0; kc < (NKC); ++kc) {                   \
      f16x8 wfr_[2];                                                           \
      _Pragma("unroll") for (int nt = 0; nt < 2; ++nt)                         \
        wfr_[nt] = *(const f16x8*)&wp[(size_t)(((UNIT0) + kc * 8 + wv * 2 + nt) * 64 + lane) * 8]; \
      _Pragma("unroll") for (int et = 0; et < 4; ++et) {                       \
        int r_ = et * 16 + cl;                                                 \
        int idx_ = r_ * (ASTR) + kc * 32 + kh * 8;                             \
        if (ASWZ) idx_ ^= ((r_ & 7) << 3);                                     \
        f16x8 efr_ = *(const f16x8*)&(APTR)[idx_];                             \
        _Pragma("unroll") for (int nt = 0; nt < 2; ++nt)                       \
          acc[nt][et] = __builtin_amdgcn_mfma_f32_16x16x32_f16(wfr_[nt], efr_, acc[nt][et], 0, 0, 0); \
      }                                                                        \
    }                                                                          \
  }

#define STORE_T(DPTR, RELU)                                                    \
  _Pragma("unroll") for (int nt = 0; nt < 2; ++nt)                             \
    _Pragma("unroll") for (int et = 0; et < 4; ++et) {                         \
      float v0_ = acc[nt][et][0], v1_ = acc[nt][et][1],                        \
            v2_ = acc[nt][et][2], v3_ = acc[nt][et][3];                        \
      if (RELU) { v0_ = fmaxf(v0_, 0.f); v1_ = fmaxf(v1_, 0.f);                \
                  v2_ = fmaxf(v2_, 0.f); v3_ = fmaxf(v3_, 0.f); }              \
      int r_ = et * 16 + cl;                                                   \
      int idx_ = (r_ * 128 + wv * 32 + nt * 16 + kh * 4) ^ ((r_ & 7) << 3);    \
      *(f16x4*)&(DPTR)[idx_] = (f16x4){(f16)v0_, (f16)v1_, (f16)v2_, (f16)v3_};\
    }

// ============================================================================
// update: h' = LN(h + MLP2([h|aggr]))  -- f16 MFMA, writes h16
// ============================================================================
__global__ __launch_bounds__(256, 2)
void update_mfma_kernel(const f16* __restrict__ h16, const float* __restrict__ aggr,
                        const f16* __restrict__ wp,
                        const float* __restrict__ b1, const float* __restrict__ b2,
                        const float* __restrict__ lng, const float* __restrict__ lnb,
                        f16* __restrict__ h16out) {
  __shared__ f16 ua[64 * 264];
  __shared__ f16 tb[64 * 128];
  __shared__ f16 emb[64 * 128];
  const int tid = threadIdx.x;
  const int lane = tid & 63;
  const int wv = tid >> 6;
  const int cl = lane & 15;
  const int kh = lane >> 4;
  const int r0 = blockIdx.x * 64;
#pragma unroll
  for (int it = 0; it < 8; ++it) {
    int f = tid + it * 256;
    int row = f >> 5, c8 = f & 31;
    int grow = r0 + row;
    f16x8 v = {};
    if (grow < NN) {
      if (c8 < 16) {
        v = *(const f16x8*)(h16 + (size_t)grow * 128 + c8 * 8);
      } else {
        const float* sp = aggr + (size_t)grow * 128 + (c8 - 16) * 8;
        float4 u0 = *(const float4*)sp, u1 = *(const float4*)(sp + 4);
        v = (f16x8){(f16)u0.x, (f16)u0.y, (f16)u0.z, (f16)u0.w,
                    (f16)u1.x, (f16)u1.y, (f16)u1.z, (f16)u1.w};
      }
    }
    *(f16x8*)&ua[row * 264 + c8 * 8] = v;
  }
  __syncthreads();
  f32x4 acc[2][4];
  MFMA_T(ua, 264, 0, 8, 0, b1);             // upd hidden, K=256
  STORE_T(tb, 1);
  __syncthreads();
  MFMA_T(tb, 128, 1, 4, 64, b2);            // h_new, K=128
  STORE_T(emb, 0);
  __syncthreads();
  {
    const int row = tid >> 2, q = tid & 3;
    const int grow = r0 + row;
    float y[32];
    float s = 0.f, ss = 0.f;
#pragma unroll
    for (int j = 0; j < 4; ++j) {
      int col = q * 32 + j * 8;
      int ei = (row * 128 + col) ^ ((row & 7) << 3);
      f16x8 ev = *(const f16x8*)&emb[ei];
      f16x8 rv = *(const f16x8*)&ua[row * 264 + col];
#pragma unroll
      for (int e = 0; e < 8; ++e) {
        float t = (float)ev[e] + (float)rv[e];
        y[j * 8 + e] = t; s += t; ss += t * t;
      }
    }
    s += __shfl_xor(s, 1);  s += __shfl_xor(s, 2);
    ss += __shfl_xor(ss, 1); ss += __shfl_xor(ss, 2);
    float mean = s * (1.f / 128.f);
    float var = ss * (1.f / 128.f) - mean * mean;
    float rstd = rsqrtf(var + 1e-5f);
    if (grow < NN) {
#pragma unroll
      for (int j = 0; j < 4; ++j) {
        int col = q * 32 + j * 8;
        const float4 g0 = *(const float4*)(lng + col), g1 = *(const float4*)(lng + col + 4);
        const float4 q0 = *(const float4*)(lnb + col), q1 = *(const float4*)(lnb + col + 4);
        float gv[8] = {g0.x, g0.y, g0.z, g0.w, g1.x, g1.y, g1.z, g1.w};
        float bv[8] = {q0.x, q0.y, q0.z, q0.w, q1.x, q1.y, q1.z, q1.w};
        f16x8 o;
#pragma unroll
        for (int e = 0; e < 8; ++e)
          o[e] = (f16)((y[j * 8 + e] - mean) * rstd * gv[e] + bv[e]);
        *(f16x8*)(h16out + (size_t)grow * 128 + col) = o;
      }
    }
  }
}

// ============================================================================
// fp32 register-tiled machinery (encoder only)
// ============================================================================
#define ACC_INIT(BPTR)                                                        \
  {                                                                           \
    const float4 bA_ = *(const float4*)((BPTR) + cg * 8);                     \
    const float4 bB_ = *(const float4*)((BPTR) + cg * 8 + 4);                 \
    _Pragma("unroll") for (int i_ = 0; i_ < 4; ++i_) {                        \
      acc[i_][0] = bA_.x; acc[i_][1] = bA_.y; acc[i_][2] = bA_.z;             \
      acc[i_][3] = bA_.w; acc[i_][4] = bB_.x; acc[i_][5] = bB_.y;             \
      acc[i_][6] = bB_.z; acc[i_][7] = bB_.w;                                 \
    }                                                                         \
  }

#define GEMM_STEP(ABUF, ASTR, WPTR)                                           \
  {                                                                           \
    const float4 w0_ = *(const float4*)((WPTR) + (size_t)k * 128 + cg * 8);   \
    const float4 w1_ = *(const float4*)((WPTR) + (size_t)k * 128 + cg * 8 + 4);\
    float wv_[8] = {w0_.x, w0_.y, w0_.z, w0_.w, w1_.x, w1_.y, w1_.z, w1_.w};  \
    float av_[4];                                                             \
    _Pragma("unroll") for (int i_ = 0; i_ < 4; ++i_)                          \
        av_[i_] = (ABUF)[(rg * 4 + i_) * (ASTR) + k];                         \
    _Pragma("unroll") for (int i_ = 0; i_ < 4; ++i_)                          \
      _Pragma("unroll") for (int j_ = 0; j_ < 8; ++j_)                        \
          acc[i_][j_] = fmaf(av_[i_], wv_[j_], acc[i_][j_]);                  \
  }

#define STORE_LDS_RELU(TBUF, TSTR)                                            \
  _Pragma("unroll") for (int i_ = 0; i_ < 4; ++i_) {                          \
    *(float4*)&(TBUF)[(rg * 4 + i_) * (TSTR) + cg * 8] =                      \
        make_float4(fmaxf(acc[i_][0], 0.f), fmaxf(acc[i_][1], 0.f),           \
                    fmaxf(acc[i_][2], 0.f), fmaxf(acc[i_][3], 0.f));          \
    *(float4*)&(TBUF)[(rg * 4 + i_) * (TSTR) + cg * 8 + 4] =                  \
        make_float4(fmaxf(acc[i_][4], 0.f), fmaxf(acc[i_][5], 0.f),           \
                    fmaxf(acc[i_][6], 0.f), fmaxf(acc[i_][7], 0.f));          \
  }

__global__ void gru_transpose_kernel(const float* __restrict__ wih,
                                     const float* __restrict__ whh,
                                     float* __restrict__ wihT,
                                     float* __restrict__ whhT) {
  int idx = blockIdx.x * 256 + threadIdx.x;
  if (idx < 128 * 384) {
    int k = idx / 384;
    int j = idx - k * 384;
    wihT[idx] = wih[j * 128 + k];
    whhT[idx] = whh[j * 128 + k];
  }
}

__global__ __launch_bounds__(256, 2)
void encoder_kernel(const float* __restrict__ x,
                    const float* __restrict__ w1, const float* __restrict__ b1,
                    const float* __restrict__ w2, const float* __restrict__ b2,
                    f16* __restrict__ h16out) {
  __shared__ float xa[64 * 132];
  __shared__ float tb[64 * 132];
  const int tid = threadIdx.x;
  const int cg = tid & 15, rg = tid >> 4;
  const int r0 = blockIdx.x * 64;
#pragma unroll
  for (int it = 0; it < 8; ++it) {
    int f = tid + it * 256;
    int row = f >> 5, c4 = f & 31;
    float4 v = make_float4(0.f, 0.f, 0.f, 0.f);
    int grow = r0 + row;
    if (grow < NN) v = *(const float4*)(x + (size_t)grow * 128 + c4 * 4);
    *(float4*)&xa[row * 132 + c4 * 4] = v;
  }
  __syncthreads();
  float acc[4][8];
  ACC_INIT(b1);
#pragma unroll 2
  for (int k = 0; k < 128; ++k) GEMM_STEP(xa, 132, w1);
  STORE_LDS_RELU(tb, 132);
  __syncthreads();
  ACC_INIT(b2);
#pragma unroll 2
  for (int k = 0; k < 128; ++k) GEMM_STEP(tb, 132, w2);
#pragma unroll
  for (int i = 0; i < 4; ++i) {
    int grow = r0 + rg * 4 + i;
    if (grow < NN) {
      f16x8 o = {(f16)acc[i][0], (f16)acc[i][1], (f16)acc[i][2], (f16)acc[i][3],
                 (f16)acc[i][4], (f16)acc[i][5], (f16)acc[i][6], (f16)acc[i][7]};
      *(f16x8*)(h16out + (size_t)grow * 128 + cg * 8) = o;
    }
  }
}

__global__ __launch_bounds__(256, 4)
void gru_kernel(const f16* __restrict__ h16, const float* __restrict__ hprev,
                const float* __restrict__ wihT, const float* __restrict__ whhT,
                const float* __restrict__ bih, const float* __restrict__ bhh,
                float* __restrict__ out) {
  __shared__ float ha[32 * 132];
  __shared__ float hp[32 * 132];
  const int tid = threadIdx.x, cg = tid & 15, rg = tid >> 4;
  const int r0 = blockIdx.x * 32;
#pragma unroll
  for (int it = 0; it < 2; ++it) {
    int f = tid + it * 256;
    int row = f >> 4, c8 = f & 15;
    int grow = r0 + row;
    f16x8 v = {};
    if (grow < NN) v = *(const f16x8*)(h16 + (size_t)grow * 128 + c8 * 8);
    float* dp = &ha[row * 132 + c8 * 8];
    *(float4*)dp = make_float4((float)v[0], (float)v[1], (float)v[2], (float)v[3]);
    *(float4*)(dp + 4) = make_float4((float)v[4], (float)v[5], (float)v[6], (float)v[7]);
  }
#pragma unroll
  for (int it = 0; it < 4; ++it) {
    int f = tid + it * 256;
    int row = f >> 5, c4 = f & 31;
    int grow = r0 + row;
    float4 vp = make_float4(0.f, 0.f, 0.f, 0.f);
    if (grow < NN) vp = *(const float4*)(hprev + (size_t)grow * 128 + c4 * 4);
    *(float4*)&hp[row * 132 + c4 * 4] = vp;
  }
  __syncthreads();
  float rgate[2][8], zgate[2][8];
#pragma unroll
  for (int c = 0; c < 2; ++c) {
    float acc[2][8];
#pragma unroll
    for (int j = 0; j < 8; ++j) {
      float bsum = bih[c * 128 + cg * 8 + j] + bhh[c * 128 + cg * 8 + j];
      acc[0][j] = bsum; acc[1][j] = bsum;
    }
    for (int k = 0; k < 128; ++k) {
      const float* wi = wihT + (size_t)k * 384 + c * 128 + cg * 8;
      const float* wh = whhT + (size_t)k * 384 + c * 128 + cg * 8;
      const float4 wi0 = *(const float4*)wi, wi1 = *(const float4*)(wi + 4);
      const float4 wh0 = *(const float4*)wh, wh1 = *(const float4*)(wh + 4);
      float wiv[8] = {wi0.x, wi0.y, wi0.z, wi0.w, wi1.x, wi1.y, wi1.z, wi1.w};
      float whv[8] = {wh0.x, wh0.y, wh0.z, wh0.w, wh1.x, wh1.y, wh1.z, wh1.w};
      float a0 = ha[(rg * 2 + 0) * 132 + k], a1 = ha[(rg * 2 + 1) * 132 + k];
      float p0 = hp[(rg * 2 + 0) * 132 + k], p1 = hp[(rg * 2 + 1) * 132 + k];
#pragma unroll
      for (int j = 0; j < 8; ++j) {
        acc[0][j] = fmaf(a0, wiv[j], acc[0][j]);
        acc[1][j] = fmaf(a1, wiv[j], acc[1][j]);
        acc[0][j] = fmaf(p0, whv[j], acc[0][j]);
        acc[1][j] = fmaf(p1, whv[j], acc[1][j]);
      }
    }
#pragma unroll
    for (int i = 0; i < 2; ++i)
#pragma unroll
      for (int j = 0; j < 8; ++j) {
        float sg = 1.f / (1.f + __expf(-acc[i][j]));
        if (c == 0) rgate[i][j] = sg; else zgate[i][j] = sg;
      }
  }
  float ai[2][8], ah[2][8];
#pragma unroll
  for (int j = 0; j < 8; ++j) {
    float bi = bih[256 + cg * 8 + j], bh = bhh[256 + cg * 8 + j];
    ai[0][j] = bi; ai[1][j] = bi;
    ah[0][j] = bh; ah[1][j] = bh;
  }
  for (int k = 0; k < 128; ++k) {
    const float* wi = wihT + (size_t)k * 384 + 256 + cg * 8;
    const float* wh = whhT + (size_t)k * 384 + 256 + cg * 8;
    const float4 wi0 = *(const float4*)wi, wi1 = *(const float4*)(wi + 4);
    const float4 wh0 = *(const float4*)wh, wh1 = *(const float4*)(wh + 4);
    float wiv[8] = {wi0.x, wi0.y, wi0.z, wi0.w, wi1.x, wi1.y, wi1.z, wi1.w};
    float whv[8] = {wh0.x, wh0.y, wh0.z, wh0.w, wh1.x, wh1.y, wh1.z, wh1.w};
    float a0 = ha[(rg * 2 + 0) * 132 + k], a1 = ha[(rg * 2 + 1) * 132 + k];
    float p0 = hp[(rg * 2 + 0) * 132 + k], p1 = hp[(rg * 2 + 1) * 132 + k];
#pragma unroll
    for (int j = 0; j < 8; ++j) {
      ai[0][j] = fmaf(a0, wiv[j], ai[0][j]);
      ai[1][j] = fmaf(a1, wiv[j], ai[1][j]);
      ah[0][j] = fmaf(p0, whv[j], ah[0][j]);
      ah[1][j] = fmaf(p1, whv[j], ah[1][j]);
    }
  }
#pragma unroll
  for (int i = 0; i < 2; ++i) {
    int grow = r0 + rg * 2 + i;
    if (grow >= NN) continue;
    float o[8];
#pragma unroll
    for (int j = 0; j < 8; ++j) {
      float nn_ = tanhf(fmaf(rgate[i][j], ah[i][j], ai[i][j]));
      float hpv = hp[(rg * 2 + i) * 132 + cg * 8 + j];
      o[j] = (1.f - zgate[i][j]) * nn_ + zgate[i][j] * hpv;
    }
    *(float4*)(out + (size_t)grow * 128 + cg * 8) = make_float4(o[0], o[1], o[2], o[3]);
    *(float4*)(out + (size_t)grow * 128 + cg * 8 + 4) = make_float4(o[4], o[5], o[6], o[7]);
  }
}

// ---------------- launch ----------------
extern "C" void kernel_launch(void* const* d_in, const int* in_sizes, int n_in,
                              void* d_out, int out_size, void* d_ws, size_t ws_size,
                              hipStream_t stream) {
  (void)in_sizes; (void)n_in; (void)out_size; (void)ws_size;
  const float* x         = (const float*)d_in[0];
  const float* edge_attr = (const float*)d_in[1];
  const float* h_prev    = (const float*)d_in[2];
  const float* enc_w1    = (const float*)d_in[3];
  const float* enc_b1    = (const float*)d_in[4];
  const float* enc_w2    = (const float*)d_in[5];
  const float* enc_b2    = (const float*)d_in[6];
  const float* et_w1     = (const float*)d_in[7];
  const float* et_b1     = (const float*)d_in[8];
  const float* et_w2     = (const float*)d_in[9];
  const float* et_b2     = (const float*)d_in[10];
  const float* msg_w1    = (const float*)d_in[11];
  const float* msg_b1    = (const float*)d_in[12];
  const float* msg_w2    = (const float*)d_in[13];
  const float* msg_b2    = (const float*)d_in[14];
  const float* upd_w1    = (const float*)d_in[15];
  const float* upd_b1    = (const float*)d_in[16];
  const float* upd_w2    = (const float*)d_in[17];
  const float* upd_b2    = (const float*)d_in[18];
  const float* ln_g      = (const float*)d_in[19];
  const float* ln_b      = (const float*)d_in[20];
  const float* gru_wih   = (const float*)d_in[21];
  const float* gru_whh   = (const float*)d_in[22];
  const float* gru_bih   = (const float*)d_in[23];
  const float* gru_bhh   = (const float*)d_in[24];
  const int* edge_index  = (const int*)d_in[25];
  const int* esrc = edge_index;        // edge_index[0]
  const int* edst = edge_index + NE;   // edge_index[1]

  float* ws   = (float*)d_ws;
  float* aggr = ws;                                  // N*128 f32
  float* wihT = ws + (size_t)NN * 128;               // 128*384
  float* whhT = wihT + 128 * 384;                    // 128*384
  f16*   h16a = (f16*)(whhT + 128 * 384);            // N*128 f16
  f16*   h16b = h16a + (size_t)NN * 128;             // N*128 f16
  f16*   wpe  = h16b + (size_t)NN * 128;             // 4*168*512 f16
  f16*   wpu  = wpe + 4 * 86016;                     // 4*96*512 f16

  gru_transpose_kernel<<<192, 256, 0, stream>>>(gru_wih, gru_whh, wihT, whhT);
  pack_w_kernel<<<(4 * 86016 + 255) / 256, 256, 0, stream>>>(et_w1, et_w2, msg_w1, msg_w2, wpe);
  pack_upd_kernel<<<(4 * 96 * 512 + 255) / 256, 256, 0, stream>>>(upd_w1, upd_w2, wpu);
  encoder_kernel<<<(NN + 63) / 64, 256, 0, stream>>>(x, enc_w1, enc_b1, enc_w2, enc_b2, h16a);

  f16* hc = h16a;
  f16* hn = h16b;
  for (int l = 0; l < 4; ++l) {
    hipMemsetAsync(aggr, 0, (size_t)NN * 128 * sizeof(float), stream);
    edge_mfma_kernel<<<NE / 64, 256, 0, stream>>>(
        hc, edge_attr, esrc, edst,
        wpe + (size_t)l * 86016,
        et_b1 + l * 128, et_b2 + l * 128,
        msg_b1 + l * 128, msg_b2 + l * 128,
        aggr);
    update_mfma_kernel<<<(NN + 63) / 64, 256, 0, stream>>>(
        hc, aggr,
        wpu + (size_t)l * 96 * 512,
        upd_b1 + l * 128, upd_b2 + l * 128,
        ln_g, ln_b, hn);
    f16* t = hc; hc = hn; hn = t;
  }
  // after 4 swaps: hc == h16a
  gru_kernel<<<(NN + 31) / 32, 256, 0, stream>>>(hc, h_prev, wihT, whhT,
                                                 gru_bih, gru_bhh, (float*)d_out);
}